// Round 2
// baseline (7719.650 us; speedup 1.0000x reference)
//
#include <hip/hip_runtime.h>
#include <hip/hip_bf16.h>

#define BB 512
#define TT 1024
#define HH 100
#define VV 62
#define BTV (512*1024*62)

// ws float offsets
#define OFF_EP  52428800   // 62*100 folded emb+bias table
#define OFF_WDT 52455200   // W_dec transposed+padded: [100][64]
#define OFF_BDP 52461800   // b_dec padded to 64

typedef float f2 __attribute__((ext_vector_type(2)));
#define PK(a,b,c) __builtin_elementwise_fma(a,b,c)

__device__ inline float tanh_fast(float x){
  float ax = fabsf(x);
  float e  = __expf(2.0f*ax);
  float r  = 1.0f - __fdividef(2.0f, e + 1.0f);
  return copysignf(r, x);
}

__global__ void prep_kernel(
    const float* __restrict__ emb, const float* __restrict__ W_ih,
    const float* __restrict__ b_ih, const float* __restrict__ b_hh,
    const float* __restrict__ W_dec, const float* __restrict__ b_dec,
    float* __restrict__ ws)
{
  int g = blockIdx.x*256 + threadIdx.x;
  if (g < 6200){
    int v = g/100, k = g%100;
    float a = b_ih[k] + b_hh[k];
    const float* er = emb + v*100;
    const float* wr = W_ih + k*100;
    for (int h=0; h<100; h++) a = fmaf(er[h], wr[h], a);
    ws[OFF_EP + v*100 + k] = a;
  } else if (g < 12600){
    int i = g - 6200;
    int h = i/64, v = i%64;
    ws[OFF_WDT + i] = (v < VV) ? W_dec[v*100 + h] : 0.f;
  } else if (g < 12664){
    int i = g - 12600;
    ws[OFF_BDP + i] = (i < VV) ? b_dec[i] : 0.f;
  }
}

// One WAVE per batch row, no barriers. Lane l owns outputs 2l,2l+1.
// Fused: while computing h_t = tanh(x_t + Wh h_{t-1}), also computes
// x^{l+1}_{t-1} = Wp h_{t-1} + bias from the SAME LDS reads (1-step skew).
__global__ __launch_bounds__(64,1) void rec_proj(
    const int* __restrict__ ids, const float* __restrict__ ep,
    const float* __restrict__ Wh, const float* __restrict__ Wp,
    const float* __restrict__ bpi, const float* __restrict__ bph,
    const float* __restrict__ xin, float* __restrict__ xout,
    float* __restrict__ hid, int use_ep)
{
  __shared__ __align__(16) float h_s[112];
  __shared__ float ep_s[6200];
  const int b = blockIdx.x, l = threadIdx.x;
  const int k0 = (l < 50) ? 2*l : 98;   // clamp; lanes>=50 compute garbage, never store

  f2 wh0[50], wh1[50], wp0[50], wp1[50];
  {
    const f2* a0 = (const f2*)(Wh + k0*100);
    const f2* a1 = (const f2*)(Wh + (k0+1)*100);
    const f2* p0 = (const f2*)(Wp + k0*100);
    const f2* p1 = (const f2*)(Wp + (k0+1)*100);
    #pragma unroll
    for (int c=0;c<50;c++){ wh0[c]=a0[c]; wh1[c]=a1[c]; wp0[c]=p0[c]; wp1[c]=p1[c]; }
  }
  f2 pbias; pbias.x = bpi[k0]+bph[k0]; pbias.y = bpi[k0+1]+bph[k0+1];

  if (use_ep){
    f2* eps2 = (f2*)ep_s;
    const f2* epg = (const f2*)ep;
    for (int i=l;i<3100;i+=64) eps2[i] = epg[i];
  }
  if (l < 56){ f2 z = {0.f,0.f}; ((f2*)h_s)[l] = z; }
  __builtin_amdgcn_wave_barrier();

  int idn = 0; f2 xn = {0.f,0.f};
  if (use_ep) idn = ids[b*TT];
  else        xn  = *(const f2*)(xin + (size_t)b*100 + k0);

  f2 hlast = {0.f,0.f};
  const f2* h2 = (const f2*)h_s;

  for (int t=0;t<TT;t++){
    f2 xcur;
    if (use_ep){
      xcur = *(const f2*)(ep_s + idn*100 + k0);
      if (t+1 < TT) idn = ids[b*TT + t + 1];
    } else {
      xcur = xn;
      if (t+1 < TT) xn = *(const f2*)(xin + ((size_t)(t+1)*BB + b)*100 + k0);
    }
    f2 r0a={0,0}, r0b={0,0}, r1a={0,0}, r1b={0,0};
    f2 q0a={0,0}, q0b={0,0}, q1a={0,0}, q1b={0,0};
    #pragma unroll
    for (int c=0;c<50;c+=2){
      f2 h0 = h2[c], h1 = h2[c+1];
      r0a = PK(wh0[c],h0,r0a); r0b = PK(wh0[c+1],h1,r0b);
      r1a = PK(wh1[c],h0,r1a); r1b = PK(wh1[c+1],h1,r1b);
      q0a = PK(wp0[c],h0,q0a); q0b = PK(wp0[c+1],h1,q0b);
      q1a = PK(wp1[c],h0,q1a); q1b = PK(wp1[c+1],h1,q1b);
    }
    if (t){
      f2 xp;
      xp.x = pbias.x + ((q0a.x+q0a.y)+(q0b.x+q0b.y));
      xp.y = pbias.y + ((q1a.x+q1a.y)+(q1b.x+q1b.y));
      if (l < 50) *(f2*)(xout + ((size_t)(t-1)*BB + b)*100 + k0) = xp;
    }
    f2 hn;
    hn.x = tanh_fast(xcur.x + ((r0a.x+r0a.y)+(r0b.x+r0b.y)));
    hn.y = tanh_fast(xcur.y + ((r1a.x+r1a.y)+(r1b.x+r1b.y)));
    hlast = hn;
    __builtin_amdgcn_wave_barrier();
    if (l < 50) ((f2*)h_s)[l] = hn;
    __builtin_amdgcn_wave_barrier();
  }

  // epilogue: projection of h_{T-1} -> x_{T-1}, and hidden finals
  {
    f2 q0a={0,0}, q0b={0,0}, q1a={0,0}, q1b={0,0};
    #pragma unroll
    for (int c=0;c<50;c+=2){
      f2 h0 = h2[c], h1 = h2[c+1];
      q0a = PK(wp0[c],h0,q0a); q0b = PK(wp0[c+1],h1,q0b);
      q1a = PK(wp1[c],h0,q1a); q1b = PK(wp1[c+1],h1,q1b);
    }
    f2 xp;
    xp.x = pbias.x + ((q0a.x+q0a.y)+(q0b.x+q0b.y));
    xp.y = pbias.y + ((q1a.x+q1a.y)+(q1b.x+q1b.y));
    if (l < 50){
      *(f2*)(xout + ((size_t)(TT-1)*BB + b)*100 + k0) = xp;
      *(f2*)(hid + (size_t)b*100 + k0) = hlast;
    }
  }
}

// Last layer: no projection; writes h_t to buf for decoder.
__global__ __launch_bounds__(64,1) void rec_last(
    const float* __restrict__ Wh, const float* __restrict__ xin,
    float* __restrict__ xout, float* __restrict__ hid)
{
  __shared__ __align__(16) float h_s[112];
  const int b = blockIdx.x, l = threadIdx.x;
  const int k0 = (l < 50) ? 2*l : 98;

  f2 wh0[50], wh1[50];
  {
    const f2* a0 = (const f2*)(Wh + k0*100);
    const f2* a1 = (const f2*)(Wh + (k0+1)*100);
    #pragma unroll
    for (int c=0;c<50;c++){ wh0[c]=a0[c]; wh1[c]=a1[c]; }
  }
  if (l < 56){ f2 z = {0.f,0.f}; ((f2*)h_s)[l] = z; }
  __builtin_amdgcn_wave_barrier();

  f2 xn = *(const f2*)(xin + (size_t)b*100 + k0);
  f2 hlast = {0.f,0.f};
  const f2* h2 = (const f2*)h_s;

  for (int t=0;t<TT;t++){
    f2 xcur = xn;
    if (t+1 < TT) xn = *(const f2*)(xin + ((size_t)(t+1)*BB + b)*100 + k0);
    f2 r0a={0,0}, r0b={0,0}, r1a={0,0}, r1b={0,0};
    #pragma unroll
    for (int c=0;c<50;c+=2){
      f2 h0 = h2[c], h1 = h2[c+1];
      r0a = PK(wh0[c],h0,r0a); r0b = PK(wh0[c+1],h1,r0b);
      r1a = PK(wh1[c],h0,r1a); r1b = PK(wh1[c+1],h1,r1b);
    }
    f2 hn;
    hn.x = tanh_fast(xcur.x + ((r0a.x+r0a.y)+(r0b.x+r0b.y)));
    hn.y = tanh_fast(xcur.y + ((r1a.x+r1a.y)+(r1b.x+r1b.y)));
    hlast = hn;
    if (l < 50) *(f2*)(xout + ((size_t)t*BB + b)*100 + k0) = hn;
    __builtin_amdgcn_wave_barrier();
    if (l < 50) ((f2*)h_s)[l] = hn;
    __builtin_amdgcn_wave_barrier();
  }
  if (l < 50) *(f2*)(hid + (size_t)b*100 + k0) = hlast;
}

// Decoder: WG = (b, 128 consecutive t). Output-coalesced, packed FMA.
__global__ __launch_bounds__(128) void dec_kernel(
    const float* __restrict__ buf, const float* __restrict__ wdt,
    const float* __restrict__ bdp, float* __restrict__ out)
{
  __shared__ float rt[100*129];
  const int tid = threadIdx.x;
  const int wg  = blockIdx.x;
  const int bb  = wg >> 3;
  const int t0  = (wg & 7) * 128;
  const float4* b4 = (const float4*)buf;

  #pragma unroll
  for (int j=0;j<25;j++){
    int f = j*128 + tid;
    int i = f/25, c = f%25;
    float4 v = b4[((size_t)(t0+i)*BB + bb)*25 + c];
    rt[(4*c+0)*129 + i] = v.x;
    rt[(4*c+1)*129 + i] = v.y;
    rt[(4*c+2)*129 + i] = v.z;
    rt[(4*c+3)*129 + i] = v.w;
  }
  __syncthreads();

  f2 acc[32];
  const f2* bd2 = (const f2*)bdp;
  #pragma unroll
  for (int j=0;j<32;j++) acc[j] = bd2[j];

  for (int h=0; h<HH; h++){
    float rv = rt[h*129 + tid];
    f2 rv2 = {rv, rv};
    const float4* w4 = (const float4*)(wdt + h*64);
    #pragma unroll
    for (int j=0;j<16;j++){
      float4 w = w4[j];
      f2 wlo = {w.x, w.y}, whi = {w.z, w.w};
      acc[2*j]   = PK(rv2, wlo, acc[2*j]);
      acc[2*j+1] = PK(rv2, whi, acc[2*j+1]);
    }
  }

  f2* o2 = (f2*)(out + (size_t)(wg*128 + tid)*VV);
  #pragma unroll
  for (int j=0;j<31;j++) o2[j] = acc[j];
}

extern "C" void kernel_launch(void* const* d_in, const int* in_sizes, int n_in,
                              void* d_out, int out_size, void* d_ws, size_t ws_size,
                              hipStream_t stream)
{
  const int*   ids   = (const int*)d_in[0];
  const float* emb   = (const float*)d_in[1];
  const float* W_ih  = (const float*)d_in[2];
  const float* W_hh  = (const float*)d_in[3];
  const float* b_ih  = (const float*)d_in[4];
  const float* b_hh  = (const float*)d_in[5];
  const float* W_dec = (const float*)d_in[6];
  const float* b_dec = (const float*)d_in[7];
  float* out = (float*)d_out;
  float* ws  = (float*)d_ws;
  float* buf = ws;                 // [T][B][100] fp32, reused in place by all layers
  float* hid = out + BTV;

  prep_kernel<<<50, 256, 0, stream>>>(emb, W_ih, b_ih, b_hh, W_dec, b_dec, ws);

  // layer 0: x from ep table, emits x^1 into buf
  rec_proj<<<BB, 64, 0, stream>>>(ids, ws+OFF_EP, W_hh, W_ih+10000,
                                  b_ih+100, b_hh+100, buf, buf, hid, 1);
  // layer 1: x from buf (in place, skew-safe), emits x^2
  rec_proj<<<BB, 64, 0, stream>>>(ids, ws+OFF_EP, W_hh+10000, W_ih+20000,
                                  b_ih+200, b_hh+200, buf, buf, hid+51200, 0);
  // layer 2: h out for decoder
  rec_last<<<BB, 64, 0, stream>>>(W_hh+20000, buf, buf, hid+102400);

  dec_kernel<<<4096, 128, 0, stream>>>(buf, ws+OFF_WDT, ws+OFF_BDP, out);
}

// Round 3
// 5674.531 us; speedup vs baseline: 1.3604x; 1.3604x over previous
//
#include <hip/hip_runtime.h>
#include <hip/hip_bf16.h>

#define BB 512
#define TT 1024
#define HH 100
#define VV 62
#define BTV (512*1024*62)

// ws float offsets
#define OFF_EP  52428800   // 62*100 folded emb+bias table
#define OFF_WIT 52435200   // W_ih^T for layers 1,2: [2][100][100] (wit[l][h][k])
#define OFF_WDT 52455200   // W_dec transposed+padded: [100][64]
#define OFF_BS  52461600   // bias sums layers 1,2: [2][100]
#define OFF_BDP 52461800   // b_dec padded to 64

typedef float f2 __attribute__((ext_vector_type(2)));
#define PK(a,b,c) __builtin_elementwise_fma(a,b,c)

__device__ inline float tanh_fast(float x){
  float ax = fabsf(x);
  float e  = __expf(2.0f*ax);
  float r  = 1.0f - __fdividef(2.0f, e + 1.0f);
  return copysignf(r, x);
}

__global__ void prep_kernel(
    const float* __restrict__ emb, const float* __restrict__ W_ih,
    const float* __restrict__ b_ih, const float* __restrict__ b_hh,
    const float* __restrict__ W_dec, const float* __restrict__ b_dec,
    float* __restrict__ ws)
{
  int g = blockIdx.x*256 + threadIdx.x;
  if (g < 6200){
    int v = g/100, k = g%100;
    float a = b_ih[k] + b_hh[k];
    const float* er = emb + v*100;
    const float* wr = W_ih + k*100;
    for (int h=0; h<100; h++) a = fmaf(er[h], wr[h], a);
    ws[OFF_EP + v*100 + k] = a;
  } else if (g < 26200){
    int i = g - 6200;
    int l = i/10000, j = i%10000;
    int h = j/100, k = j%100;
    ws[OFF_WIT + i] = W_ih[(l+1)*10000 + k*100 + h];
  } else if (g < 32600){
    int i = g - 26200;
    int h = i/64, v = i%64;
    ws[OFF_WDT + i] = (v < VV) ? W_dec[v*100 + h] : 0.f;
  } else if (g < 32800){
    int i = g - 32600;
    int l = i/100, k = i%100;
    ws[OFF_BS + i] = b_ih[(l+1)*100 + k] + b_hh[(l+1)*100 + k];
  } else if (g < 32864){
    int i = g - 32800;
    ws[OFF_BDP + i] = (i < VV) ? b_dec[i] : 0.f;
  }
}

// One WAVE per TWO batch rows (same-layer rows share Wh in VGPRs).
// Lane l owns outputs k=2l,2l+1 for both rows. No s_barrier anywhere.
// Two independent recurrence chains interleave to hide LDS/VALU latency.
__global__ __launch_bounds__(64,1) void rec2(
    const int* __restrict__ ids, const float* __restrict__ ep,
    const float* __restrict__ Wh, const float* __restrict__ xin,
    float* __restrict__ xout, float* __restrict__ hid, int use_ep)
{
  __shared__ __align__(16) float hA_s[112];
  __shared__ __align__(16) float hB_s[112];
  __shared__ float ep_s[6200];
  const int l  = threadIdx.x;
  const int bA = 2*blockIdx.x, bB = bA + 1;
  const int k0 = (l < 50) ? 2*l : 98;   // lanes >=50 duplicate, never store

  f2 wh0[50], wh1[50];
  {
    const f2* a0 = (const f2*)(Wh + k0*100);
    const f2* a1 = (const f2*)(Wh + (k0+1)*100);
    #pragma unroll
    for (int c=0;c<50;c++){ wh0[c]=a0[c]; wh1[c]=a1[c]; }
  }
  if (use_ep){
    f2* e2 = (f2*)ep_s; const f2* eg = (const f2*)ep;
    for (int i=l;i<3100;i+=64) e2[i]=eg[i];
  }
  if (l < 56){ f2 z={0.f,0.f}; ((f2*)hA_s)[l]=z; ((f2*)hB_s)[l]=z; }
  __builtin_amdgcn_wave_barrier();

  // x prefetch ring, depth 2 (covers ~900cyc HBM latency at ~700cyc/step)
  f2 xA0,xA1,xB0,xB1; int idA2=0, idB2=0;
  if (use_ep){
    int ia0=ids[bA*TT], ia1=ids[bA*TT+1];
    int ib0=ids[bB*TT], ib1=ids[bB*TT+1];
    idA2=ids[bA*TT+2]; idB2=ids[bB*TT+2];
    xA0=*(const f2*)(ep_s+ia0*100+k0); xA1=*(const f2*)(ep_s+ia1*100+k0);
    xB0=*(const f2*)(ep_s+ib0*100+k0); xB1=*(const f2*)(ep_s+ib1*100+k0);
  } else {
    xA0=*(const f2*)(xin+(size_t)(bA)*100+k0);
    xA1=*(const f2*)(xin+((size_t)BB+bA)*100+k0);
    xB0=*(const f2*)(xin+(size_t)(bB)*100+k0);
    xB1=*(const f2*)(xin+((size_t)BB+bB)*100+k0);
  }

  f2 hlA={0.f,0.f}, hlB={0.f,0.f};
  const f2* h2A=(const f2*)hA_s;
  const f2* h2B=(const f2*)hB_s;

  for (int t=0;t<TT;t++){
    f2 xcA=xA0, xcB=xB0;
    xA0=xA1; xB0=xB1;
    if (use_ep){
      xA1=*(const f2*)(ep_s+idA2*100+k0);        // x(t+2)
      xB1=*(const f2*)(ep_s+idB2*100+k0);
      int tn = (t+3<TT)? t+3 : TT-1;
      idA2=ids[bA*TT+tn]; idB2=ids[bB*TT+tn];
    } else {
      int tn = (t+2<TT)? t+2 : TT-1;
      xA1=*(const f2*)(xin+((size_t)tn*BB+bA)*100+k0);
      xB1=*(const f2*)(xin+((size_t)tn*BB+bB)*100+k0);
    }
    f2 r0a={0,0},r0b={0,0},r1a={0,0},r1b={0,0};
    f2 s0a={0,0},s0b={0,0},s1a={0,0},s1b={0,0};
    #pragma unroll
    for (int c=0;c<50;c+=2){
      f2 hA0=h2A[c], hA1=h2A[c+1];
      f2 hB0=h2B[c], hB1=h2B[c+1];
      r0a=PK(wh0[c],hA0,r0a); r0b=PK(wh0[c+1],hA1,r0b);
      r1a=PK(wh1[c],hA0,r1a); r1b=PK(wh1[c+1],hA1,r1b);
      s0a=PK(wh0[c],hB0,s0a); s0b=PK(wh0[c+1],hB1,s0b);
      s1a=PK(wh1[c],hB0,s1a); s1b=PK(wh1[c+1],hB1,s1b);
    }
    f2 hnA, hnB;
    hnA.x=tanh_fast(xcA.x+((r0a.x+r0a.y)+(r0b.x+r0b.y)));
    hnA.y=tanh_fast(xcA.y+((r1a.x+r1a.y)+(r1b.x+r1b.y)));
    hnB.x=tanh_fast(xcB.x+((s0a.x+s0a.y)+(s0b.x+s0b.y)));
    hnB.y=tanh_fast(xcB.y+((s1a.x+s1a.y)+(s1b.x+s1b.y)));
    hlA=hnA; hlB=hnB;
    __builtin_amdgcn_wave_barrier();
    if (l < 50){ ((f2*)hA_s)[l]=hnA; ((f2*)hB_s)[l]=hnB; }
    __builtin_amdgcn_wave_barrier();
    if (l < 50){
      *(f2*)(xout+((size_t)t*BB+bA)*100+k0)=hnA;
      *(f2*)(xout+((size_t)t*BB+bB)*100+k0)=hnB;
    }
  }
  if (l < 50){
    *(f2*)(hid+(size_t)bA*100+k0)=hlA;
    *(f2*)(hid+(size_t)bB*100+k0)=hlB;
  }
}

// In-place rows x Wi^T + bias, f2-packed accumulators.
__global__ __launch_bounds__(128) void ffn_gemm(
    float* __restrict__ buf, const float* __restrict__ wt,
    const float* __restrict__ bsum)
{
  __shared__ float rt[100*129];
  const int tid = threadIdx.x;
  const size_t rowbase = (size_t)blockIdx.x * 128;
  float4* bin4 = (float4*)(buf + rowbase*HH);

  #pragma unroll
  for (int j=0;j<25;j++){
    int f = j*128 + tid;
    int r = f/25, c = f%25;
    float4 v = bin4[f];
    rt[(4*c+0)*129 + r] = v.x;
    rt[(4*c+1)*129 + r] = v.y;
    rt[(4*c+2)*129 + r] = v.z;
    rt[(4*c+3)*129 + r] = v.w;
  }
  __syncthreads();

  f2 acc[50];
  const f2* bs2 = (const f2*)bsum;
  #pragma unroll
  for (int j=0;j<50;j++) acc[j] = bs2[j];

  for (int h=0; h<HH; h++){
    float rv = rt[h*129 + tid];
    f2 rv2 = {rv, rv};
    const f2* w2 = (const f2*)(wt + h*HH);
    #pragma unroll
    for (int j=0;j<50;j++) acc[j] = PK(rv2, w2[j], acc[j]);
  }
  __syncthreads();   // everyone done reading input rows

  #pragma unroll
  for (int j=0;j<50;j++){
    rt[(2*j+0)*129 + tid] = acc[j].x;
    rt[(2*j+1)*129 + tid] = acc[j].y;
  }
  __syncthreads();

  #pragma unroll
  for (int j=0;j<25;j++){
    int f = j*128 + tid;
    int r = f/25, c = f%25;
    float4 v;
    v.x = rt[(4*c+0)*129 + r];
    v.y = rt[(4*c+1)*129 + r];
    v.z = rt[(4*c+2)*129 + r];
    v.w = rt[(4*c+3)*129 + r];
    bin4[f] = v;
  }
}

// Decoder: WG = (b, 128 consecutive t). Output-coalesced, packed FMA.
__global__ __launch_bounds__(128) void dec_kernel(
    const float* __restrict__ buf, const float* __restrict__ wdt,
    const float* __restrict__ bdp, float* __restrict__ out)
{
  __shared__ float rt[100*129];
  const int tid = threadIdx.x;
  const int wg  = blockIdx.x;
  const int bb  = wg >> 3;
  const int t0  = (wg & 7) * 128;
  const float4* b4 = (const float4*)buf;

  #pragma unroll
  for (int j=0;j<25;j++){
    int f = j*128 + tid;
    int i = f/25, c = f%25;
    float4 v = b4[((size_t)(t0+i)*BB + bb)*25 + c];
    rt[(4*c+0)*129 + i] = v.x;
    rt[(4*c+1)*129 + i] = v.y;
    rt[(4*c+2)*129 + i] = v.z;
    rt[(4*c+3)*129 + i] = v.w;
  }
  __syncthreads();

  f2 acc[32];
  const f2* bd2 = (const f2*)bdp;
  #pragma unroll
  for (int j=0;j<32;j++) acc[j] = bd2[j];

  for (int h=0; h<HH; h++){
    float rv = rt[h*129 + tid];
    f2 rv2 = {rv, rv};
    const f2* w2 = (const f2*)(wdt + h*64);
    #pragma unroll
    for (int j=0;j<32;j++) acc[j] = PK(rv2, w2[j], acc[j]);
  }

  f2* o2 = (f2*)(out + (size_t)(wg*128 + tid)*VV);
  #pragma unroll
  for (int j=0;j<31;j++) o2[j] = acc[j];
}

extern "C" void kernel_launch(void* const* d_in, const int* in_sizes, int n_in,
                              void* d_out, int out_size, void* d_ws, size_t ws_size,
                              hipStream_t stream)
{
  const int*   ids   = (const int*)d_in[0];
  const float* emb   = (const float*)d_in[1];
  const float* W_ih  = (const float*)d_in[2];
  const float* W_hh  = (const float*)d_in[3];
  const float* b_ih  = (const float*)d_in[4];
  const float* b_hh  = (const float*)d_in[5];
  const float* W_dec = (const float*)d_in[6];
  const float* b_dec = (const float*)d_in[7];
  float* out = (float*)d_out;
  float* ws  = (float*)d_ws;
  float* buf = ws;                 // [T][B][100] fp32, reused in place
  float* hid = out + BTV;

  prep_kernel<<<129, 256, 0, stream>>>(emb, W_ih, b_ih, b_hh, W_dec, b_dec, ws);

  rec2<<<256, 64, 0, stream>>>(ids, ws+OFF_EP, W_hh,         buf, buf, hid,        1);
  ffn_gemm<<<4096, 128, 0, stream>>>(buf, ws+OFF_WIT,         ws+OFF_BS);
  rec2<<<256, 64, 0, stream>>>(ids, ws+OFF_EP, W_hh + 10000, buf, buf, hid+ 51200, 0);
  ffn_gemm<<<4096, 128, 0, stream>>>(buf, ws+OFF_WIT + 10000, ws+OFF_BS + 100);
  rec2<<<256, 64, 0, stream>>>(ids, ws+OFF_EP, W_hh + 20000, buf, buf, hid+102400, 0);
  dec_kernel<<<4096, 128, 0, stream>>>(buf, ws+OFF_WDT, ws+OFF_BDP, out);
}